// Round 1
// baseline (698.721 us; speedup 1.0000x reference)
//
#include <hip/hip_runtime.h>

// Problem constants: B=2, S=2048 -> T=4096 tokens; D=1024, H=4096, E=8, top-2.
#define T_TOK 4096
#define DIM   1024
#define HID   4096
#define NEXP  8
#define MAXROWS 9216

typedef unsigned short u16;
typedef __attribute__((ext_vector_type(8))) short short8;   // 8 bf16 (4 VGPRs) MFMA frag
typedef __attribute__((ext_vector_type(4))) float f32x4;
typedef __attribute__((ext_vector_type(2))) unsigned short u16x2;
typedef __attribute__((ext_vector_type(4))) unsigned short u16x4;
typedef __attribute__((ext_vector_type(8))) unsigned short u16x8;

typedef __attribute__((address_space(3))) unsigned int lds_uint;
typedef const __attribute__((address_space(1))) unsigned int gbl_uint;

__device__ __forceinline__ u16 f2bf(float f) {
    union { float f; unsigned int u; } v; v.f = f;
    unsigned int r = v.u + 0x7fffu + ((v.u >> 16) & 1u);   // RNE
    return (u16)(r >> 16);
}

// fast gelu (tanh form): max |err| vs exact erf-gelu ~3e-4, well under budget
__device__ __forceinline__ float gelu_f(float v) {
    float u = 1.5957691216f * (v + 0.044715f * v * v * v);   // 2*0.7978845608*(...)
    float s = 1.0f / (1.0f + __expf(-u));                    // sigmoid(2u') == 0.5*(1+tanh(u'))
    return v * s;
}

// ---------------- fused transpose+cast for BOTH weights; also zeroes counts.
// fp32 [R][C] -> bf16 [C][R] per expert. 128x128 tiles (load segs 512B, store segs 256B).
// blockIdx.x in [0,4096): first 2048 blocks w1 (R=1024,C=4096); rest w2 (R=4096,C=1024).
__global__ __launch_bounds__(256)
void transpose_cast2(const float* __restrict__ w1, u16* __restrict__ w1t,
                     const float* __restrict__ w2, u16* __restrict__ w2t,
                     int* __restrict__ counts) {
    int b = blockIdx.x;
    if (b == 0 && threadIdx.x < NEXP) counts[threadIdx.x] = 0;
    const float* in; u16* out; int R, C, bx, by, e;
    if (b < 2048) {
        e = b >> 8; int t = b & 255; bx = t & 31; by = t >> 5;   // 32 x (C/128), 8 y (R/128)
        in = w1; out = w1t; R = DIM; C = HID;
    } else {
        b -= 2048;
        e = b >> 8; int t = b & 255; bx = t & 7; by = t >> 3;    // 8 x, 32 y
        in = w2; out = w2t; R = HID; C = DIM;
    }
    __shared__ u16 tl[128 * 130];    // stride 130 u16: 4B-aligned, breaks pow2 banks
    size_t mo = (size_t)e * DIM * HID;
    const float* ip = in + mo;
    u16* op = out + mo;
    int c0 = bx * 128, r0 = by * 128;
    int tid = threadIdx.x;
#pragma unroll
    for (int j = 0; j < 16; ++j) {
        int id = tid + 256 * j;
        int r = id >> 5, cg = id & 31;                           // row, 16B col-group
        f32x4 v = *(const f32x4*)(ip + (size_t)(r0 + r) * C + c0 + 4 * cg);
        u16x2 wa; wa.x = f2bf(v.x); wa.y = f2bf(v.y);
        u16x2 wb; wb.x = f2bf(v.z); wb.y = f2bf(v.w);
        *(u16x2*)(tl + r * 130 + 4 * cg)     = wa;
        *(u16x2*)(tl + r * 130 + 4 * cg + 2) = wb;
    }
    __syncthreads();
#pragma unroll
    for (int j = 0; j < 8; ++j) {
        int id = tid + 256 * j;
        int c = id >> 4, ch = id & 15;                           // out row, 16B chunk
        u16x8 o;
#pragma unroll
        for (int k = 0; k < 8; ++k) o[k] = tl[(ch * 8 + k) * 130 + c];
        *(u16x8*)(op + (size_t)(c0 + c) * R + r0 + ch * 8) = o;
    }
}

// ---------------- router: logits -> softmax -> top2 -> renormalized gates
__global__ __launch_bounds__(256)
void router_k(const float* __restrict__ x, const float* __restrict__ rw,
              int* __restrict__ counts, int* __restrict__ tE,
              int* __restrict__ tS, float* __restrict__ tG) {
    int wave = threadIdx.x >> 6, lane = threadIdx.x & 63;
    int t = blockIdx.x * 4 + wave;
    const float* xr = x + (size_t)t * DIM;
    float xv[16];
#pragma unroll
    for (int i = 0; i < 16; ++i) xv[i] = xr[lane + 64*i];
    float lg[NEXP];
#pragma unroll
    for (int e = 0; e < NEXP; ++e) {
        const float* wr_ = rw + e * DIM;
        float a = 0.f;
#pragma unroll
        for (int i = 0; i < 16; ++i) a += xv[i] * wr_[lane + 64*i];
        lg[e] = a;
    }
#pragma unroll
    for (int off = 32; off > 0; off >>= 1)
#pragma unroll
        for (int e = 0; e < NEXP; ++e) lg[e] += __shfl_xor(lg[e], off, 64);
    if (lane == 0) {
        float mx = lg[0];
        for (int e = 1; e < NEXP; ++e) mx = fmaxf(mx, lg[e]);
        float p[NEXP], s = 0.f;
        for (int e = 0; e < NEXP; ++e) { p[e] = expf(lg[e] - mx); s += p[e]; }
        float inv_s = 1.f / s;
        for (int e = 0; e < NEXP; ++e) p[e] *= inv_s;
        int i0 = 0;
        for (int e = 1; e < NEXP; ++e) if (p[e] > p[i0]) i0 = e;
        int i1 = (i0 == 0) ? 1 : 0;
        for (int e = 0; e < NEXP; ++e) if (e != i0 && p[e] > p[i1]) i1 = e;
        float v0 = p[i0], v1 = p[i1];
        float inv = 1.f / (v0 + v1 + 1e-9f);
        int s0 = atomicAdd(&counts[i0], 1);
        int s1 = atomicAdd(&counts[i1], 1);
        tE[2*t] = i0;  tE[2*t+1] = i1;
        tS[2*t] = s0;  tS[2*t+1] = s1;
        tG[2*t] = v0 * inv;  tG[2*t+1] = v1 * inv;
    }
}

// inline exclusive scan of 128-padded counts: returns base for expert e
__device__ __forceinline__ int pbase_of(const int* __restrict__ counts, int e) {
    int pb = 0;
#pragma unroll
    for (int i = 0; i < NEXP; ++i) {
        int pad = ((counts[i] + 127) >> 7) << 7;
        pb += (i < e) ? pad : 0;
    }
    return pb;
}

// ---------------- gather x rows (fp32) into packed bf16 rows per assignment
__global__ __launch_bounds__(256)
void gather_k(const float* __restrict__ x, const int* __restrict__ tE,
              const int* __restrict__ tS, const int* __restrict__ counts,
              u16* __restrict__ xg) {
    int a = blockIdx.x;              // 0..8191
    int t = a >> 1, k = a & 1;
    int e = tE[2*t + k];
    int row = pbase_of(counts, e) + tS[2*t + k];
    const f32x4* xr = (const f32x4*)(x + (size_t)t * DIM);
    u16x4* o = (u16x4*)(xg + (size_t)row * DIM);
    int i = threadIdx.x;             // 256 threads x 4 floats = 1024
    f32x4 v = xr[i];
    u16x4 r; r.x = f2bf(v.x); r.y = f2bf(v.y); r.z = f2bf(v.z); r.w = f2bf(v.w);
    o[i] = r;
}

// ---------------- grouped GEMM: C[row][col] = A[row][K_sub] * Bt[col][K_sub]  (per expert)
// 256x256 tile, BK=64, 8 waves (2Mx4N), double-buffered LDS (128 KiB), 4 compute
// phases per K-tile (16 MFMA each, setprio-wrapped), raw s_barrier + counted waits:
// next K-tile staged at phase 1 via global_load_lds, stays in flight across all 4
// phase barriers, single vmcnt(0) per K-tile at phase 4 (~2400cyc after issue, free).
// XOR-swizzled 16B chunks in LDS (conflict-free, carried over from 128^2 version).
template<int K, int KSPLIT, bool GELU, typename OutT>
__global__ __launch_bounds__(512, 2)
void gemm_bt(const u16* __restrict__ A, const u16* __restrict__ BtAll,
             OutT* __restrict__ C, const int* __restrict__ counts,
             int N, size_t cstride) {
    int e  = blockIdx.z / KSPLIT;
    int ks = blockIdx.z % KSPLIT;
    int cnt = counts[e];
    int mt = blockIdx.y;
    if (mt * 256 >= cnt) return;
    int row0 = pbase_of(counts, e) + mt * 256;
    int limit = cnt - mt * 256;          // valid rows in this block (BM=256 > 128 pad)
    const u16* Bt = BtAll + (size_t)e * N * K;
    OutT* Cp = C + (size_t)ks * cstride;
    int col0 = blockIdx.x * 256;
    const int kb0 = ks * (K / KSPLIT);
    constexpr int NT = K / KSPLIT / 64;  // K-tiles

    // 128 KiB: A0 [0,16K) A1 [16K,32K) B0 [32K,48K) B1 [48K,64K) in u16 units
    __shared__ __align__(16) u16 smem[65536];

    int tid = threadIdx.x;
    int lane = tid & 63;
    int w = tid >> 6;                    // 0..7
    int quad = lane >> 4, m16 = lane & 15;
    int wr = (w >> 2) * 128, wc = (w & 3) * 64;   // wave's output sub-tile origin
    int rsub = lane >> 3;                // 0..7: row within an 8-row staging group
    int kch  = lane & 7;                 // 16B chunk within row (LDS slot)
    int kchs = kch ^ rsub;               // swizzled GLOBAL chunk fetched into that slot

    // staging pointers (bumped +64 elem = 128 B per K-tile); A rows clamped to ws
    const u16* ga[4];
    const u16* gb[4];
#pragma unroll
    for (int i = 0; i < 4; ++i) {
        int g = (w << 2) + i;
        int ra = row0 + g * 8 + rsub;
        if (ra > MAXROWS - 1) ra = MAXROWS - 1;      // tile may overhang padded rows
        ga[i] = A  + (size_t)ra * K + kb0 + kchs * 8;
        gb[i] = Bt + (size_t)(col0 + g * 8 + rsub) * K + kb0 + kchs * 8;
    }
    // fragment read offsets: row&7 == m16&7 for all frags (16 | row steps)
    int sw = m16 & 7;
    const int aoff = (wr + m16) * 64;
    const int boff = (wc + m16) * 64;
    const int c0lo = (quad ^ sw) << 3;           // k-step 0 chunk
    const int c0hi = ((4 + quad) ^ sw) << 3;     // k-step 1 chunk

    f32x4 acc[8][4] = {};

    // prologue: stage K-tile 0 into buf 0, drain, barrier
#pragma unroll
    for (int i = 0; i < 4; ++i) {
        int g = (w << 2) + i;
        __builtin_amdgcn_global_load_lds((gbl_uint*)ga[i], (lds_uint*)(smem + g * 512), 16, 0, 0);
        __builtin_amdgcn_global_load_lds((gbl_uint*)gb[i], (lds_uint*)(smem + 32768 + g * 512), 16, 0, 0);
        ga[i] += 64; gb[i] += 64;
    }
    asm volatile("s_waitcnt vmcnt(0)" ::: "memory");
    __builtin_amdgcn_s_barrier();

#pragma unroll 2
    for (int t = 0; t < NT; ++t) {
        const u16* Ab = smem + (t & 1) * 16384;
        const u16* Bb = smem + 32768 + (t & 1) * 16384;
        short8 a0[4], a1[4], b0[4], b1[4];
        // ---- phase 1: stage next K-tile; read A m0-3 + B n0-1; MFMA quad(m0-3,n0-1)
        if (t + 1 < NT) {
#pragma unroll
            for (int i = 0; i < 4; ++i) {
                int g = (w << 2) + i;
                __builtin_amdgcn_global_load_lds((gbl_uint*)ga[i],
                    (lds_uint*)(smem + ((t + 1) & 1) * 16384 + g * 512), 16, 0, 0);
                __builtin_amdgcn_global_load_lds((gbl_uint*)gb[i],
                    (lds_uint*)(smem + 32768 + ((t + 1) & 1) * 16384 + g * 512), 16, 0, 0);
                ga[i] += 64; gb[i] += 64;
            }
        }
#pragma unroll
        for (int m = 0; m < 4; ++m) {
            a0[m] = *(const short8*)(Ab + aoff + m * 1024 + c0lo);
            a1[m] = *(const short8*)(Ab + aoff + m * 1024 + c0hi);
        }
#pragma unroll
        for (int n = 0; n < 2; ++n) {
            b0[n] = *(const short8*)(Bb + boff + n * 1024 + c0lo);
            b1[n] = *(const short8*)(Bb + boff + n * 1024 + c0hi);
        }
        __builtin_amdgcn_s_barrier();
        asm volatile("s_waitcnt lgkmcnt(0)" ::: "memory");
        __builtin_amdgcn_s_setprio(1);
#pragma unroll
        for (int m = 0; m < 4; ++m)
#pragma unroll
            for (int n = 0; n < 2; ++n) {
                acc[m][n] = __builtin_amdgcn_mfma_f32_16x16x32_bf16(a0[m], b0[n], acc[m][n], 0, 0, 0);
                acc[m][n] = __builtin_amdgcn_mfma_f32_16x16x32_bf16(a1[m], b1[n], acc[m][n], 0, 0, 0);
            }
        __builtin_amdgcn_s_setprio(0);
        __builtin_amdgcn_s_barrier();
        // ---- phase 2: read B n2-3; MFMA quad(m0-3,n2-3)
#pragma unroll
        for (int n = 2; n < 4; ++n) {
            b0[n] = *(const short8*)(Bb + boff + n * 1024 + c0lo);
            b1[n] = *(const short8*)(Bb + boff + n * 1024 + c0hi);
        }
        __builtin_amdgcn_s_barrier();
        asm volatile("s_waitcnt lgkmcnt(0)" ::: "memory");
        __builtin_amdgcn_s_setprio(1);
#pragma unroll
        for (int m = 0; m < 4; ++m)
#pragma unroll
            for (int n = 2; n < 4; ++n) {
                acc[m][n] = __builtin_amdgcn_mfma_f32_16x16x32_bf16(a0[m], b0[n], acc[m][n], 0, 0, 0);
                acc[m][n] = __builtin_amdgcn_mfma_f32_16x16x32_bf16(a1[m], b1[n], acc[m][n], 0, 0, 0);
            }
        __builtin_amdgcn_s_setprio(0);
        __builtin_amdgcn_s_barrier();
        // ---- phase 3: read A m4-7; MFMA quad(m4-7,n2-3)
#pragma unroll
        for (int m = 0; m < 4; ++m) {
            a0[m] = *(const short8*)(Ab + aoff + (4 + m) * 1024 + c0lo);
            a1[m] = *(const short8*)(Ab + aoff + (4 + m) * 1024 + c0hi);
        }
        __builtin_amdgcn_s_barrier();
        asm volatile("s_waitcnt lgkmcnt(0)" ::: "memory");
        __builtin_amdgcn_s_setprio(1);
#pragma unroll
        for (int m = 0; m < 4; ++m)
#pragma unroll
            for (int n = 2; n < 4; ++n) {
                acc[4 + m][n] = __builtin_amdgcn_mfma_f32_16x16x32_bf16(a0[m], b0[n], acc[4 + m][n], 0, 0, 0);
                acc[4 + m][n] = __builtin_amdgcn_mfma_f32_16x16x32_bf16(a1[m], b1[n], acc[4 + m][n], 0, 0, 0);
            }
        __builtin_amdgcn_s_setprio(0);
        __builtin_amdgcn_s_barrier();
        // ---- phase 4: MFMA quad(m4-7,n0-1); wait staged K-tile; barrier
        __builtin_amdgcn_s_setprio(1);
#pragma unroll
        for (int m = 0; m < 4; ++m)
#pragma unroll
            for (int n = 0; n < 2; ++n) {
                acc[4 + m][n] = __builtin_amdgcn_mfma_f32_16x16x32_bf16(a0[m], b0[n], acc[4 + m][n], 0, 0, 0);
                acc[4 + m][n] = __builtin_amdgcn_mfma_f32_16x16x32_bf16(a1[m], b1[n], acc[4 + m][n], 0, 0, 0);
            }
        __builtin_amdgcn_s_setprio(0);
        asm volatile("s_waitcnt vmcnt(0)" ::: "memory");
        __builtin_amdgcn_s_barrier();
    }

    // epilogue: C/D layout col=lane&15, row=quad*4+reg (verified mapping)
    if (GELU) {
        // stage bf16 256x256 tile in LDS (XOR-swizzled 16B chunks), coalesced u16x8 stores
#pragma unroll
        for (int mi = 0; mi < 8; ++mi) {
#pragma unroll
            for (int r = 0; r < 4; ++r) {
                int row = wr + mi * 16 + quad * 4 + r;
#pragma unroll
                for (int ni = 0; ni < 4; ++ni) {
                    int col = wc + ni * 16 + m16;
                    int ch = col >> 3, w8 = col & 7;
                    smem[row * 256 + (((ch ^ (row & 31)) << 3) | w8)] = f2bf(gelu_f(acc[mi][ni][r]));
                }
            }
        }
        __syncthreads();
        int rr = tid >> 5, ch = tid & 31;
#pragma unroll
        for (int it = 0; it < 16; ++it) {
            int row = it * 16 + rr;
            if (row < limit) {
                u16x8 v = *(const u16x8*)(smem + row * 256 + ((ch ^ (row & 31)) << 3));
                *(u16x8*)((u16*)Cp + (size_t)(row0 + row) * N + col0 + ch * 8) = v;
            }
        }
    } else {
#pragma unroll
        for (int mi = 0; mi < 8; ++mi)
#pragma unroll
            for (int r = 0; r < 4; ++r) {
                int rl = wr + mi * 16 + quad * 4 + r;
                if (rl < limit) {
                    float* rp = (float*)Cp + (size_t)(row0 + rl) * N + col0 + wc + m16;
#pragma unroll
                    for (int ni = 0; ni < 4; ++ni)
                        rp[ni * 16] = acc[mi][ni][r];
                }
            }
    }
}

// ---------------- combine: out[t] = g0*(p0+p1)[row0(t)] + g1*(p0+p1)[row1(t)]
__global__ __launch_bounds__(256)
void combine_k(const float* __restrict__ p0, const float* __restrict__ p1,
               const int* __restrict__ tE, const int* __restrict__ tS,
               const float* __restrict__ tG, const int* __restrict__ counts,
               float* __restrict__ out) {
    int t = blockIdx.x;
    int e0 = tE[2*t], e1 = tE[2*t+1];
    int r0 = pbase_of(counts, e0) + tS[2*t];
    int r1 = pbase_of(counts, e1) + tS[2*t+1];
    float g0 = tG[2*t], g1 = tG[2*t+1];
    int i = threadIdx.x;
    f32x4 a0 = ((const f32x4*)(p0 + (size_t)r0 * DIM))[i];
    f32x4 b0 = ((const f32x4*)(p1 + (size_t)r0 * DIM))[i];
    f32x4 a1 = ((const f32x4*)(p0 + (size_t)r1 * DIM))[i];
    f32x4 b1 = ((const f32x4*)(p1 + (size_t)r1 * DIM))[i];
    f32x4* o = (f32x4*)(out + (size_t)t * DIM);
    o[i] = g0 * (a0 + b0) + g1 * (a1 + b1);
}

extern "C" void kernel_launch(void* const* d_in, const int* in_sizes, int n_in,
                              void* d_out, int out_size, void* d_ws, size_t ws_size,
                              hipStream_t stream) {
    const float* x  = (const float*)d_in[0];   // [4096,1024]
    const float* rw = (const float*)d_in[1];   // [8,1024]
    const float* w1 = (const float*)d_in[2];   // [8,1024,4096]
    const float* w2 = (const float*)d_in[3];   // [8,4096,1024]
    float* out = (float*)d_out;

    char* ws = (char*)d_ws;
    // layout (bytes):
    u16* w1t = (u16*)(ws + 0);                 // bf16 [E][H][D]   67,108,864
    u16* xg  = (u16*)(ws + 67108864ull);       // bf16 [9216][D]   18,874,368 -> 85,983,232
    u16* w2t = (u16*)(ws + 85983232ull);       // bf16 [E][D][H]   67,108,864 -> 153,092,096
    u16* hb  = (u16*)(ws + 153092096ull);      // bf16 [9216][H]   75,497,472 -> 228,589,568
    // fc2 split-K partials alias w1t+xg (dead after fc1): 2 x 37,748,736 = 75,497,472 <= 85,983,232
    float* p0 = (float*)(ws + 0);
    float* p1 = (float*)(ws + 37748736ull);
    int* ctrl   = (int*)(ws + 228589568ull);
    int* counts = ctrl;            // 8
    int* tE     = ctrl + 32;       // 8192
    int* tS     = ctrl + 32 + 8192;
    float* tG   = (float*)(ctrl + 32 + 16384);

    // fused transposes (+ counts zeroing, block 0)
    transpose_cast2<<<4096, 256, 0, stream>>>(w1, w1t, w2, w2t, counts);
    router_k<<<T_TOK / 4, 256, 0, stream>>>(x, rw, counts, tE, tS, tG);
    gather_k<<<T_TOK * 2, 256, 0, stream>>>(x, tE, tS, counts, xg);
    // fc1 + gelu: [rows x 1024] @ [1024 x 4096] -> hb (bf16)
    gemm_bt<DIM, 1, true, u16><<<dim3(HID / 256, 16, NEXP), 512, 0, stream>>>(
        xg, w1t, hb, counts, HID, 0);
    // fc2 split-K=2: [rows x 4096] @ [4096 x 1024] -> p0/p1 (f32)
    gemm_bt<HID, 2, false, float><<<dim3(DIM / 256, 16, NEXP * 2), 512, 0, stream>>>(
        hb, w2t, p0, counts, DIM, (size_t)MAXROWS * DIM);
    combine_k<<<T_TOK, 256, 0, stream>>>(p0, p1, tE, tS, tG, counts, out);
}